// Round 11
// baseline (316.623 us; speedup 1.0000x reference)
//
#include <hip/hip_runtime.h>
#include <math.h>

#define NN 50000
#define EE 800000
#define ET (EE + NN)   // 850000 edges incl. self-loops
#define C  64
#define NBLK 49        // ceil(NN/1024) scan blocks
#define NCHUNK 831     // ceil(ET/1024) edge chunks
#define ZBLK 463       // zeroing blocks appended to scatter

typedef __attribute__((ext_vector_type(8))) _Float16 f16x8;
typedef __attribute__((ext_vector_type(4))) _Float16 f16x4;
typedef __attribute__((ext_vector_type(2))) _Float16 f16x2;
typedef __attribute__((ext_vector_type(4))) float f32x4;

__device__ __forceinline__ f16x2 pk2(float a, float b) {
  return __builtin_bit_cast(f16x2, __builtin_amdgcn_cvt_pkrtz(a, b));
}
__device__ __forceinline__ f16x4 pk4(float a, float b, float c, float d) {
  return __builtin_shufflevector(pk2(a, b), pk2(c, d), 0, 1, 2, 3);
}
__device__ __forceinline__ f16x8 pk8(const float* y) {
  const f16x4 lo = pk4(y[0], y[1], y[2], y[3]);
  const f16x4 hi = pk4(y[4], y[5], y[6], y[7]);
  return __builtin_shufflevector(lo, hi, 0, 1, 2, 3, 4, 5, 6, 7);
}

// f16 LDS row read: 8 consecutive k at 16B alignment (stride 72 halves)
__device__ __forceinline__ f16x8 frag_ldh(const _Float16* base, int row,
                                          int kofs) {
  return *(const f16x8*)(base + row * 72 + kofs);
}

// Copy one 64x64 f16 weight from global (row-major 64) to LDS (stride 72).
__device__ __forceinline__ void stage_w(_Float16* __restrict__ dst,
                                        const _Float16* __restrict__ src16,
                                        int tid) {
  const f16x8* src = (const f16x8*)(src16 + tid * 16);
  _Float16* d = dst + (tid >> 2) * 72 + (tid & 3) * 16;
  ((f16x8*)d)[0] = src[0];
  ((f16x8*)d)[1] = src[1];
}

// pairb swizzle (stride 65): 2-way banks on read (coeff 3c), ~2-way on write
__device__ __forceinline__ int psl(int e, int o) {
  return (e + 2 * o + (o >> 5)) & 63;
}

// ---------------------------------------------------------------------------
// prep: convert 8 weight matrices f32 -> f16 (one block each) + zero cnt shards
// order: W_in, W_lin, W_src, W_dst, att_w1, att_w2, pos_w2, W_out
// ---------------------------------------------------------------------------
__global__ __launch_bounds__(256) void prep_kernel(
    const float* __restrict__ W_in, const float* __restrict__ W_lin,
    const float* __restrict__ W_src, const float* __restrict__ W_dst,
    const float* __restrict__ att_w1, const float* __restrict__ att_w2,
    const float* __restrict__ pos_w2, const float* __restrict__ W_out,
    _Float16* __restrict__ w16, int* __restrict__ cnt2) {
  const float* Ws[8] = {W_in, W_lin, W_src, W_dst, att_w1, att_w2, pos_w2, W_out};
  const float* src = Ws[blockIdx.x];
  _Float16* dst = w16 + blockIdx.x * 4096;
#pragma unroll
  for (int i = threadIdx.x * 4; i < 4096; i += 1024) {
    const float4 w = *(const float4*)(src + i);
    *(f16x4*)(dst + i) = pk4(w.x, w.y, w.z, w.w);
  }
  int4* cz = (int4*)(cnt2 + blockIdx.x * NN);
#pragma unroll 1
  for (int i = threadIdx.x; i < NN / 4; i += 256) cz[i] = make_int4(0, 0, 0, 0);
}

// ---------------------------------------------------------------------------
// Merged scan: each block re-derives its global prefix directly from cnt2,
// then writes per-(shard,node) cursor bases. One dispatch, 49 blocks.
// ---------------------------------------------------------------------------
__global__ __launch_bounds__(256) void scan_kernel(const int* __restrict__ cnt2,
                                                   int* __restrict__ curs2) {
  __shared__ int tsum[256];
  __shared__ int redbuf[4];
  const int t = threadIdx.x;
  const int b = blockIdx.x;

  // 1) base = total count of nodes [0, b*1024) across all 8 shards
  int psum = 0;
  const int lim = b * 1024;  // multiple of 4, <= 49152 < NN
#pragma unroll 1
  for (int i = t * 4; i < lim; i += 1024) {
#pragma unroll
    for (int sh = 0; sh < 8; ++sh) {
      const int4 v = *(const int4*)(cnt2 + sh * NN + i);
      psum += v.x + v.y + v.z + v.w;
    }
  }
#pragma unroll
  for (int off = 32; off; off >>= 1) psum += __shfl_down(psum, off, 64);
  if ((t & 63) == 0) redbuf[t >> 6] = psum;
  __syncthreads();
  const int base = redbuf[0] + redbuf[1] + redbuf[2] + redbuf[3];

  // 2) per-node local prefix within this block's 1024 nodes
  const int nb = b * 1024 + t * 4;
  int c2[8][4];
  int v[4] = {0, 0, 0, 0};
  if (nb + 3 < NN) {
#pragma unroll
    for (int sh = 0; sh < 8; ++sh) {
      const int4 x = *(const int4*)(cnt2 + sh * NN + nb);
      c2[sh][0] = x.x; c2[sh][1] = x.y; c2[sh][2] = x.z; c2[sh][3] = x.w;
      v[0] += x.x; v[1] += x.y; v[2] += x.z; v[3] += x.w;
    }
  } else {
#pragma unroll
    for (int sh = 0; sh < 8; ++sh)
#pragma unroll
      for (int i = 0; i < 4; ++i) {
        const int c = (nb + i < NN) ? cnt2[sh * NN + nb + i] : 0;
        c2[sh][i] = c;
        v[i] += c;
      }
  }
  const int s = v[0] + v[1] + v[2] + v[3];
  tsum[t] = s;
  __syncthreads();
  for (int off = 1; off < 256; off <<= 1) {
    const int u = (t >= off) ? tsum[t - off] : 0;
    __syncthreads();
    tsum[t] += u;
    __syncthreads();
  }
  int ex = base + tsum[t] - s;
  int offs[8][4];
#pragma unroll
  for (int i = 0; i < 4; ++i) {
    int run = ex;
#pragma unroll
    for (int sh = 0; sh < 8; ++sh) {
      offs[sh][i] = run;
      run += c2[sh][i];
    }
    ex += v[i];
  }
  if (nb + 3 < NN) {
#pragma unroll
    for (int sh = 0; sh < 8; ++sh)
      *(int4*)(curs2 + sh * NN + nb) =
          make_int4(offs[sh][0], offs[sh][1], offs[sh][2], offs[sh][3]);
  } else {
#pragma unroll
    for (int sh = 0; sh < 8; ++sh)
#pragma unroll
      for (int i = 0; i < 4; ++i)
        if (nb + i < NN) curs2[sh * NN + nb + i] = offs[sh][i];
  }
}

// scatter: block b owns edge chunk b (1024 edges); shard = b&7 (XCD-aligned).
// Blocks >= NCHUNK zero num/den (must complete before edge_pass).
__global__ __launch_bounds__(256) void scatter_kernel(const int* __restrict__ ei,
                                                      int* __restrict__ curs2,
                                                      int2* __restrict__ srt,
                                                      float* __restrict__ zeroreg) {
  const int chunk = blockIdx.x;
  if (chunk >= NCHUNK) {
    const int zb = chunk - NCHUNK;
    float4* dst = (float4*)zeroreg;
    const int total4 = 2 * NN * 64 / 4;
    const float4 z = make_float4(0.f, 0.f, 0.f, 0.f);
#pragma unroll 1
    for (int i = zb * 256 + threadIdx.x; i < total4; i += ZBLK * 256) dst[i] = z;
    return;
  }
  int* cs = curs2 + (chunk & 7) * NN;
  const int e0 = chunk * 1024 + threadIdx.x * 4;
  if (e0 >= ET) return;
  int s[4], d[4];
  if (e0 + 3 < EE) {
    const int4 sv = *(const int4*)(ei + e0);
    const int4 dv = *(const int4*)(ei + EE + e0);
    s[0] = sv.x; s[1] = sv.y; s[2] = sv.z; s[3] = sv.w;
    d[0] = dv.x; d[1] = dv.y; d[2] = dv.z; d[3] = dv.w;
  } else {
#pragma unroll
    for (int i = 0; i < 4; ++i) {
      const int e = e0 + i;
      if (e < EE) {
        s[i] = ei[e];
        d[i] = ei[EE + e];
      } else if (e < ET) {
        s[i] = d[i] = e - EE;
      } else {
        s[i] = d[i] = -1;
      }
    }
  }
#pragma unroll
  for (int i = 0; i < 4; ++i) {
    if (d[i] >= 0) {
      const int p = atomicAdd(&cs[d[i]], 1);
      srt[p] = make_int2(s[i], d[i]);
    }
  }
}

// ---------------------------------------------------------------------------
// Kernel A: fused sharded histogram + node projections (MFMA f16).
// ---------------------------------------------------------------------------
__global__ __launch_bounds__(256, 3) void node_proj(
    const float* __restrict__ x, const float* __restrict__ b_in,
    const _Float16* __restrict__ w16, const int* __restrict__ ei,
    int* __restrict__ cnt2, _Float16* __restrict__ vh,
    _Float16* __restrict__ kh, _Float16* __restrict__ qh) {
  __shared__ __align__(16) _Float16 wlds[4 * 4608];  // W_in|W_lin|W_src|W_dst
  __shared__ __align__(16) _Float16 hlds[4608];
  __shared__ float biasv[64];

  const int tid = threadIdx.x;
  const int nb = blockIdx.x * 64;
  const int l15 = tid & 15;
  const int quad = (tid >> 4) & 3;
  const int wband = tid >> 6;
  const int nloc = wband * 16 + l15;
  const int gn = nb + nloc;

  // sharded fire-and-forget histogram; chunk c = edges [c*1024,(c+1)*1024)
#pragma unroll 1
  for (int chunk = blockIdx.x; chunk < NCHUNK; chunk += gridDim.x) {
    int* cs = cnt2 + (chunk & 7) * NN;
    const int e0 = chunk * 1024 + tid * 4;
    if (e0 < ET) {
      int d[4];
      if (e0 + 3 < EE) {
        const int4 dv = *(const int4*)(ei + EE + e0);
        d[0] = dv.x; d[1] = dv.y; d[2] = dv.z; d[3] = dv.w;
      } else {
#pragma unroll
        for (int i = 0; i < 4; ++i) {
          const int e = e0 + i;
          d[i] = (e < EE) ? ei[EE + e] : ((e < ET) ? e - EE : -1);
        }
      }
#pragma unroll
      for (int i = 0; i < 4; ++i)
        if (d[i] >= 0) atomicAdd(&cs[d[i]], 1);
    }
  }

#pragma unroll
  for (int w = 0; w < 4; ++w) stage_w(wlds + w * 4608, w16 + w * 4096, tid);
  if (tid < 64) biasv[tid] = b_in[tid];

  // B-frag from x (f32 -> f16)
  f16x8 bfrag[2];
#pragma unroll
  for (int ks = 0; ks < 2; ++ks) {
    float y[8] = {0.f, 0.f, 0.f, 0.f, 0.f, 0.f, 0.f, 0.f};
    if (gn < NN) {
      const float4 a = *(const float4*)(x + (size_t)gn * 64 + ks * 32 + quad * 8);
      const float4 b = *(const float4*)(x + (size_t)gn * 64 + ks * 32 + quad * 8 + 4);
      y[0] = a.x; y[1] = a.y; y[2] = a.z; y[3] = a.w;
      y[4] = b.x; y[5] = b.y; y[6] = b.z; y[7] = b.w;
    }
    bfrag[ks] = pk8(y);
  }
  __syncthreads();  // B0

  // GEMM1: h = relu(W_in . x^T + b) -> hlds rows [n][o] f16
#pragma unroll
  for (int t = 0; t < 4; ++t) {
    f32x4 acc = {0.f, 0.f, 0.f, 0.f};
#pragma unroll
    for (int ks = 0; ks < 2; ++ks) {
      const f16x8 af = frag_ldh(wlds, t * 16 + l15, ks * 32 + quad * 8);
      acc = __builtin_amdgcn_mfma_f32_16x16x32_f16(af, bfrag[ks], acc, 0, 0, 0);
    }
    const int hb = t * 16 + quad * 4;
    *(f16x4*)(hlds + nloc * 72 + hb) =
        pk4(fmaxf(acc[0] + biasv[hb + 0], 0.f), fmaxf(acc[1] + biasv[hb + 1], 0.f),
            fmaxf(acc[2] + biasv[hb + 2], 0.f), fmaxf(acc[3] + biasv[hb + 3], 0.f));
  }
  __syncthreads();  // B1

  f16x8 hfrag[2];
#pragma unroll
  for (int ks = 0; ks < 2; ++ks)
    hfrag[ks] = frag_ldh(hlds, nloc, ks * 32 + quad * 8);

  _Float16* outs[3] = {vh, kh, qh};
#pragma unroll
  for (int p = 0; p < 3; ++p) {
    const _Float16* W = wlds + (p + 1) * 4608;
#pragma unroll
    for (int t = 0; t < 4; ++t) {
      f32x4 acc = {0.f, 0.f, 0.f, 0.f};
#pragma unroll
      for (int ks = 0; ks < 2; ++ks) {
        const f16x8 af = frag_ldh(W, t * 16 + l15, ks * 32 + quad * 8);
        acc = __builtin_amdgcn_mfma_f32_16x16x32_f16(af, hfrag[ks], acc, 0, 0, 0);
      }
      if (gn < NN) {
        *(f16x4*)(outs[p] + (size_t)gn * 64 + t * 16 + quad * 4) =
            pk4(acc[0], acc[1], acc[2], acc[3]);
      }
    }
  }
}

// ---------------------------------------------------------------------------
// Kernel B: MFMA (f16) edge pass. LDS ~29.7KB -> 5 blocks/CU. 4 barriers.
//  - W1 | W2 | HP(h1 then PW2), each 64 rows x stride 72 f16
//  - h1 is wave-private -> no barrier between GEMM1 and GEMM2
//  - pairb: f16x2 (msg,ex), stride 65 (16.6KB), aliases W1+W2 after B1
// ---------------------------------------------------------------------------
__global__ __launch_bounds__(256, 5) void edge_pass(
    const int2* __restrict__ srt, const float* __restrict__ pos,
    const _Float16* __restrict__ vh, const _Float16* __restrict__ kh,
    const _Float16* __restrict__ qh, const _Float16* __restrict__ w16,
    const float* __restrict__ att_b1, const float* __restrict__ att_b2,
    const float* __restrict__ pos_w1, const float* __restrict__ pos_b1,
    const float* __restrict__ pos_b2, float* __restrict__ num,
    float* __restrict__ den) {
  __shared__ __align__(16) _Float16 smem[13824];  // W1|W2|HP
  __shared__ __align__(16) float posw1T[3 * 64];
  __shared__ float b1s[64], b2s[64], pb1s[64], pb2s[64];
  __shared__ int dsts[64];

  _Float16* W1 = smem;
  _Float16* W2 = smem + 4608;
  _Float16* HP = smem + 9216;     // h1, then PW2
  f16x2* pairb = (f16x2*)smem;    // 64ch x stride65 = 16640B <= 18432B (W1+W2)

  const int tid = threadIdx.x;
  const int eb = blockIdx.x * 64;
  const int l15 = tid & 15;
  const int quad = (tid >> 4) & 3;
  const int wband = tid >> 6;
  const int eloc = wband * 16 + l15;

  // ---- phase 0a: per-lane edge read + B-frag: ad = q[dst]-k[src] (f16)
  int s_mine, d_mine;
  f16x8 bfrag[2];
  float dp0, dp1, dp2;
  {
    const int e = eb + eloc;
    int2 sd = make_int2(0, 0);
    int valid_d = -1;
    if (e < ET) {
      sd = srt[e];
      valid_d = sd.y;
    }
    s_mine = sd.x;
    d_mine = sd.y;
    if (quad == 0) dsts[eloc] = valid_d;
#pragma unroll
    for (int ks = 0; ks < 2; ++ks) {
      const f16x8 qv =
          *(const f16x8*)(qh + (size_t)d_mine * 64 + ks * 32 + quad * 8);
      const f16x8 kv =
          *(const f16x8*)(kh + (size_t)s_mine * 64 + ks * 32 + quad * 8);
      bfrag[ks] = qv - kv;
    }
    dp0 = pos[(size_t)d_mine * 3 + 0] - pos[(size_t)s_mine * 3 + 0];
    dp1 = pos[(size_t)d_mine * 3 + 1] - pos[(size_t)s_mine * 3 + 1];
    dp2 = pos[(size_t)d_mine * 3 + 2] - pos[(size_t)s_mine * 3 + 2];
  }

  // ---- phase 0b: stage W1, W2 (f16), biases, posw1T
  stage_w(W1, w16 + 4 * 4096, tid);
  stage_w(W2, w16 + 5 * 4096, tid);
  if (tid < 64) {
    b1s[tid] = att_b1[tid];
    b2s[tid] = att_b2[tid];
    pb1s[tid] = pos_b1[tid];
    pb2s[tid] = pos_b2[tid];
    posw1T[0 * 64 + tid] = pos_w1[tid * 3 + 0];
    posw1T[1 * 64 + tid] = pos_w1[tid * 3 + 1];
    posw1T[2 * 64 + tid] = pos_w1[tid * 3 + 2];
  }
  __syncthreads();  // B0

  // ---- GEMM1: h1 = relu(W1 . ad^T + b1) -> HP rows [e][h] f16 (wave-private)
#pragma unroll
  for (int t = 0; t < 4; ++t) {
    f32x4 acc = {0.f, 0.f, 0.f, 0.f};
#pragma unroll
    for (int ks = 0; ks < 2; ++ks) {
      const f16x8 af = frag_ldh(W1, t * 16 + l15, ks * 32 + quad * 8);
      acc = __builtin_amdgcn_mfma_f32_16x16x32_f16(af, bfrag[ks], acc, 0, 0, 0);
    }
    const int hb = t * 16 + quad * 4;
    *(f16x4*)(HP + eloc * 72 + hb) =
        pk4(fmaxf(acc[0] + b1s[hb + 0], 0.f), fmaxf(acc[1] + b1s[hb + 1], 0.f),
            fmaxf(acc[2] + b1s[hb + 2], 0.f), fmaxf(acc[3] + b1s[hb + 3], 0.f));
  }

  // ---- hp in registers (k=3 pos-MLP layer 1 for this lane's 16 k-values)
  f16x8 hpfrag[2];
#pragma unroll
  for (int ks = 0; ks < 2; ++ks) {
    float hv[8];
#pragma unroll
    for (int j = 0; j < 8; ++j) {
      const int i = ks * 32 + quad * 8 + j;
      float h = pb1s[i];
      h = fmaf(dp0, posw1T[i], h);
      h = fmaf(dp1, posw1T[64 + i], h);
      h = fmaf(dp2, posw1T[128 + i], h);
      hv[j] = fmaxf(h, 0.f);
    }
    hpfrag[ks] = pk8(hv);
  }

  // ---- GEMM2: alpha = relu(W2 . h1^T + b2); ex = exp(alpha)
  float ex[16];
  {
    f16x8 hfrag[2];
#pragma unroll
    for (int ks = 0; ks < 2; ++ks)
      hfrag[ks] = frag_ldh(HP, eloc, ks * 32 + quad * 8);
#pragma unroll
    for (int t = 0; t < 4; ++t) {
      f32x4 acc = {0.f, 0.f, 0.f, 0.f};
#pragma unroll
      for (int ks = 0; ks < 2; ++ks) {
        const f16x8 af = frag_ldh(W2, t * 16 + l15, ks * 32 + quad * 8);
        acc = __builtin_amdgcn_mfma_f32_16x16x32_f16(af, hfrag[ks], acc, 0, 0, 0);
      }
      const int ob = t * 16 + quad * 4;
#pragma unroll
      for (int r = 0; r < 4; ++r)
        ex[t * 4 + r] = __expf(fmaxf(acc[r] + b2s[ob + r], 0.f));
    }
  }
  // v gather issued now (global; overlaps B1/stage/B2 latency)
  float vr[16];
#pragma unroll
  for (int t = 0; t < 4; ++t) {
    const f16x4 v4 = *(const f16x4*)(vh + (size_t)s_mine * 64 + t * 16 + quad * 4);
    vr[t * 4 + 0] = (float)v4[0];
    vr[t * 4 + 1] = (float)v4[1];
    vr[t * 4 + 2] = (float)v4[2];
    vr[t * 4 + 3] = (float)v4[3];
  }
  __syncthreads();  // B1: all waves done with W1, W2, h1

  stage_w(HP, w16 + 6 * 4096, tid);  // PW2 over h1
  __syncthreads();  // B2: PW2 visible

  // ---- GEMM3: delta = relu(PW2 . hp^T + pb2)
  float del[16];
#pragma unroll
  for (int t = 0; t < 4; ++t) {
    f32x4 acc = {0.f, 0.f, 0.f, 0.f};
#pragma unroll
    for (int ks = 0; ks < 2; ++ks) {
      const f16x8 af = frag_ldh(HP, t * 16 + l15, ks * 32 + quad * 8);
      acc = __builtin_amdgcn_mfma_f32_16x16x32_f16(af, hpfrag[ks], acc, 0, 0, 0);
    }
    const int ob = t * 16 + quad * 4;
#pragma unroll
    for (int r = 0; r < 4; ++r)
      del[t * 4 + r] = fmaxf(acc[r] + pb2s[ob + r], 0.f);
  }

  // ---- phase 5: (msg, ex) -> pairb f16x2, stride 65 (region free since B1)
#pragma unroll
  for (int t = 0; t < 4; ++t) {
#pragma unroll
    for (int r = 0; r < 4; ++r) {
      const int o = t * 16 + quad * 4 + r;
      const float e_ = ex[t * 4 + r];
      pairb[o * 65 + psl(eloc, o)] =
          pk2(e_ * (vr[t * 4 + r] + del[t * 4 + r]), e_);
    }
  }
  __syncthreads();  // B3

  // ---- phase 6: segmented reduce over sorted-dst runs, then atomics
  {
    const int c = tid & 63;
    const int r = tid >> 6;
    float am = 0.f, ae = 0.f;
    int cur = -1;
#pragma unroll 1
    for (int t2 = 0; t2 < 16; ++t2) {
      const int el = r * 16 + t2;
      const int d = dsts[el];
      if (d != cur) {
        if (cur >= 0) {
          unsafeAtomicAdd(num + (size_t)cur * 64 + c, am);
          unsafeAtomicAdd(den + (size_t)cur * 64 + c, ae);
        }
        cur = d;
        am = 0.f;
        ae = 0.f;
      }
      if (d >= 0) {
        const f16x2 pe = pairb[c * 65 + psl(el, c)];
        am += (float)pe[0];
        ae += (float)pe[1];
      }
    }
    if (cur >= 0) {
      unsafeAtomicAdd(num + (size_t)cur * 64 + c, am);
      unsafeAtomicAdd(den + (size_t)cur * 64 + c, ae);
    }
  }
}

// ---------------------------------------------------------------------------
// Kernel C: out = relu((num/(den+1e-16)) @ W_out.T + b_out), MFMA f16.
// ---------------------------------------------------------------------------
__global__ __launch_bounds__(256, 4) void out_proj(
    const float* __restrict__ num, const float* __restrict__ den,
    const _Float16* __restrict__ w16, const float* __restrict__ b_out,
    float* __restrict__ out) {
  __shared__ __align__(16) _Float16 wlds[4608];
  __shared__ float biasv[64];

  const int tid = threadIdx.x;
  const int nb = blockIdx.x * 64;
  const int l15 = tid & 15;
  const int quad = (tid >> 4) & 3;
  const int wband = tid >> 6;
  const int gn = nb + wband * 16 + l15;

  stage_w(wlds, w16 + 7 * 4096, tid);
  if (tid < 64) biasv[tid] = b_out[tid];

  f16x8 bfrag[2];
#pragma unroll
  for (int ks = 0; ks < 2; ++ks) {
    float y[8] = {0.f, 0.f, 0.f, 0.f, 0.f, 0.f, 0.f, 0.f};
    if (gn < NN) {
      const size_t base = (size_t)gn * 64 + ks * 32 + quad * 8;
      const float4 n0 = *(const float4*)(num + base);
      const float4 n1 = *(const float4*)(num + base + 4);
      const float4 d0 = *(const float4*)(den + base);
      const float4 d1 = *(const float4*)(den + base + 4);
      y[0] = n0.x / (d0.x + 1e-16f); y[1] = n0.y / (d0.y + 1e-16f);
      y[2] = n0.z / (d0.z + 1e-16f); y[3] = n0.w / (d0.w + 1e-16f);
      y[4] = n1.x / (d1.x + 1e-16f); y[5] = n1.y / (d1.y + 1e-16f);
      y[6] = n1.z / (d1.z + 1e-16f); y[7] = n1.w / (d1.w + 1e-16f);
    }
    bfrag[ks] = pk8(y);
  }
  __syncthreads();

#pragma unroll
  for (int t = 0; t < 4; ++t) {
    f32x4 acc = {0.f, 0.f, 0.f, 0.f};
#pragma unroll
    for (int ks = 0; ks < 2; ++ks) {
      const f16x8 af = frag_ldh(wlds, t * 16 + l15, ks * 32 + quad * 8);
      acc = __builtin_amdgcn_mfma_f32_16x16x32_f16(af, bfrag[ks], acc, 0, 0, 0);
    }
    if (gn < NN) {
      const int ob = t * 16 + quad * 4;
      float4 r;
      r.x = fmaxf(acc[0] + biasv[ob + 0], 0.f);
      r.y = fmaxf(acc[1] + biasv[ob + 1], 0.f);
      r.z = fmaxf(acc[2] + biasv[ob + 2], 0.f);
      r.w = fmaxf(acc[3] + biasv[ob + 3], 0.f);
      *(float4*)(out + (size_t)gn * 64 + ob) = r;
    }
  }
}

extern "C" void kernel_launch(void* const* d_in, const int* in_sizes, int n_in,
                              void* d_out, int out_size, void* d_ws,
                              size_t ws_size, hipStream_t stream) {
  const float* x      = (const float*)d_in[0];
  const float* pos    = (const float*)d_in[1];
  const int*   ei     = (const int*)d_in[2];
  const float* W_in   = (const float*)d_in[3];
  const float* b_in   = (const float*)d_in[4];
  const float* W_out  = (const float*)d_in[5];
  const float* b_out  = (const float*)d_in[6];
  const float* W_lin  = (const float*)d_in[7];
  const float* W_src  = (const float*)d_in[8];
  const float* W_dst  = (const float*)d_in[9];
  const float* pos_w1 = (const float*)d_in[10];
  const float* pos_b1 = (const float*)d_in[11];
  const float* pos_w2 = (const float*)d_in[12];
  const float* pos_b2 = (const float*)d_in[13];
  const float* att_w1 = (const float*)d_in[14];
  const float* att_b1 = (const float*)d_in[15];
  const float* att_w2 = (const float*)d_in[16];
  const float* att_b2 = (const float*)d_in[17];

  float* ws = (float*)d_ws;
  const size_t NC = (size_t)NN * C;
  float* num = ws;                       // NC f32
  float* den = ws + NC;                  // NC f32
  _Float16* vh = (_Float16*)(ws + 2 * NC);  // NC f16
  _Float16* kh = vh + NC;                    // NC f16
  _Float16* qh = kh + NC;                    // NC f16
  _Float16* w16 = qh + NC;                   // 8*4096 f16
  int* ib     = (int*)(w16 + 8 * 4096);
  int* cnt2   = ib;                      // 8*NN
  int* curs2  = ib + 8 * NN;             // 8*NN
  int2* srt   = (int2*)(((uintptr_t)(ib + 16 * NN) + 15) & ~(uintptr_t)15);

  const dim3 blk(256);
  prep_kernel<<<dim3(8), blk, 0, stream>>>(W_in, W_lin, W_src, W_dst, att_w1,
                                           att_w2, pos_w2, W_out, w16, cnt2);
  node_proj<<<dim3((NN + 63) / 64), blk, 0, stream>>>(x, b_in, w16, ei, cnt2,
                                                      vh, kh, qh);
  scan_kernel<<<dim3(NBLK), blk, 0, stream>>>(cnt2, curs2);
  scatter_kernel<<<dim3(NCHUNK + ZBLK), blk, 0, stream>>>(ei, curs2, srt, num);
  edge_pass<<<dim3((ET + 63) / 64), blk, 0, stream>>>(
      srt, pos, vh, kh, qh, w16, att_b1, att_b2, pos_w1, pos_b1, pos_b2, num,
      den);
  out_proj<<<dim3((NN + 63) / 64), blk, 0, stream>>>(num, den, w16, b_out,
                                                     (float*)d_out);
}